// Round 2
// baseline (88.306 us; speedup 1.0000x reference)
//
#include <hip/hip_runtime.h>
#include <math.h>

// GATLayerTemporal: N=4, H=16, W=16, T=32, V=32, HW=256
// e[n,i,j,2m] = s[n,i,m]; e[n,i,j,2m+1] = s[n,j,m]
// s[n,v,m] = sum_{w<16,t<32} Wh[n,v,m*16+w,t] * a[w*32+t]
// out[n,c,t',i] = elu( sum_j G_t'[i,j] * Wh[n,j,c,t'] ),
//   G_t'[i,j] = sum_v adjn[v,i] * att_t'[v,j]
//
// ws: WhT [N][T][HW][V] (1048576 f32) | s [N][V][16] (2048 f32, atomicAdd, memset 0)

#define ALPHA 0.2f

// ---- Kernel A: per (n,c) 32x32 GEMM tile; fused s-logit atomics; coalesced WhT ----
__global__ __launch_bounds__(256) void k_whs(const float* __restrict__ h,
                                             const float* __restrict__ Wm,
                                             const float* __restrict__ a,
                                             float* __restrict__ WhT,
                                             float* __restrict__ s_g) {
    __shared__ float ht[1024];   // [t][v]
    __shared__ float Wl[1024];   // [t][tp]
    __shared__ float S[32 * 33]; // [tp][v], padded
    int tid = threadIdx.x, bid = blockIdx.x;
    int n = bid >> 8, c = bid & 255;
    int w = c & 15, m = c >> 4;
    ((float4*)ht)[tid] = ((const float4*)(h + ((size_t)(n * 256 + c)) * 1024))[tid];
    ((float4*)Wl)[tid] = ((const float4*)Wm)[tid];
    __syncthreads();
    int tp = tid & 31, v0 = tid >> 5;
    float acc[4] = {0.f, 0.f, 0.f, 0.f};
#pragma unroll
    for (int t = 0; t < 32; ++t) {
        float wl = Wl[t * 32 + tp];
#pragma unroll
        for (int p = 0; p < 4; ++p)
            acc[p] = fmaf(ht[t * 32 + v0 + 8 * p], wl, acc[p]);
    }
    float av = a[w * 32 + tp];
#pragma unroll
    for (int p = 0; p < 4; ++p) {
        S[tp * 33 + v0 + 8 * p] = acc[p];
        float contrib = acc[p] * av;
        // reduce over tp within the 32-lane half-wave
#pragma unroll
        for (int msk = 1; msk <= 16; msk <<= 1) contrib += __shfl_xor(contrib, msk);
        if (tp == 0) atomicAdd(&s_g[(n * 32 + v0 + 8 * p) * 16 + m], contrib);
    }
    __syncthreads();
#pragma unroll
    for (int p = 0; p < 4; ++p) {
        int r = (tid >> 5) + 8 * p, vc = tid & 31;
        WhT[(((size_t)(n * 32 + r)) * 256 + c) * 32 + vc] = S[r * 33 + vc];
    }
}

// ---- Kernel B: per (n,t') block does adjnorm + softmax stats + attention + G + output ----
__global__ __launch_bounds__(256) void k_outf(const float* __restrict__ WhT,
                                              const float* __restrict__ s_g,
                                              const float* __restrict__ B,
                                              float* __restrict__ out) {
    __shared__ float wht[8192];  // [c][j]
    __shared__ float adjn[1024]; // raw then normalized [v][i]
    __shared__ float Aat[1024];  // attention [v][j]
    __shared__ float gt[1024];   // [j][i]
    __shared__ float u[512];     // lrelu'd s for this n: [v][16]
    __shared__ float mxs[32], Es[32], dis[32];
    __shared__ float red[8];
    __shared__ float mnmx[2];
    int tid = threadIdx.x, bid = blockIdx.x;
    int n = bid >> 5, tp = bid & 31;
    int m = tp >> 1, odd = tp & 1;
    const float4* src = (const float4*)(WhT + ((size_t)(n * 32 + tp)) * 8192);
#pragma unroll
    for (int k = 0; k < 8; ++k) ((float4*)wht)[tid + 256 * k] = src[tid + 256 * k];

    // stage B_adj (+eps +eye), local min/max
    float4 b4 = ((const float4*)B)[tid];
    float lmn = 1e30f, lmx = -1e30f;
    const float* b4f = (const float*)&b4;
#pragma unroll
    for (int k = 0; k < 4; ++k) {
        int e = tid * 4 + k;
        float x = b4f[k] + 1e-6f + (((e >> 5) == (e & 31)) ? 1.0f : 0.0f);
        lmn = fminf(lmn, x); lmx = fmaxf(lmx, x);
        adjn[e] = x;
    }
    for (int msk = 1; msk < 64; msk <<= 1) {
        lmn = fminf(lmn, __shfl_xor(lmn, msk));
        lmx = fmaxf(lmx, __shfl_xor(lmx, msk));
    }
    if ((tid & 63) == 0) { red[tid >> 6] = lmn; red[4 + (tid >> 6)] = lmx; }

    // u = leaky_relu(s[n])
    {
        float s0 = s_g[n * 512 + tid];
        float s1 = s_g[n * 512 + 256 + tid];
        u[tid] = s0 > 0.f ? s0 : ALPHA * s0;
        u[tid + 256] = s1 > 0.f ? s1 : ALPHA * s1;
    }
    __syncthreads();
    if (tid == 0) {
        float mn = fminf(fminf(red[0], red[1]), fminf(red[2], red[3]));
        float mx = fmaxf(fmaxf(red[4], red[5]), fmaxf(red[6], red[7]));
        mnmx[0] = mn; mnmx[1] = 1.0f / (mx - mn);
    }
    __syncthreads();
    float mn = mnmx[0], inv = mnmx[1];
    if (tid < 32) {
        float rs = 0.f;
#pragma unroll
        for (int k = 0; k < 32; ++k) {
            int i = (k + tid) & 31; // staggered: conflict-free
            rs += (adjn[tid * 32 + i] - mn) * inv;
        }
        dis[tid] = rsqrtf(rs);
    } else if (tid >= 64 && tid < 96) {
        int v = tid - 64;
        float mxv = -1e30f;
#pragma unroll
        for (int k = 0; k < 16; ++k) mxv = fmaxf(mxv, u[v * 16 + k]);
        float es = 0.f;
#pragma unroll
        for (int k = 0; k < 16; ++k) es += expf(u[v * 16 + k] - mxv);
        mxs[v] = mxv; Es[v] = es;
    }
    __syncthreads();
    // normalize adjn in place; compute attention
    {
        int j = tid & 31, v0g = tid >> 5;
#pragma unroll
        for (int k = 0; k < 4; ++k) {
            int e = tid * 4 + k;
            adjn[e] = (adjn[e] - mn) * inv * dis[e >> 5] * dis[e & 31];
        }
#pragma unroll
        for (int p = 0; p < 4; ++p) {
            int v = v0g + 8 * p;
            float mv = mxs[v], mj = mxs[j];
            float M = fmaxf(mv, mj);
            float Z = Es[v] * expf(mv - M) + Es[j] * expf(mj - M);
            float num = expf((odd ? u[j * 16 + m] : u[v * 16 + m]) - M);
            Aat[v * 32 + j] = num / Z;
        }
    }
    __syncthreads();
    // gt[j][i] = sum_v adjn[v,i] * Aat[v,j]
    {
        int i = tid & 31, j0 = tid >> 5;
#pragma unroll
        for (int p = 0; p < 4; ++p) {
            int j = j0 + 8 * p;
            float acc = 0.f;
#pragma unroll
            for (int v = 0; v < 32; ++v)
                acc = fmaf(adjn[v * 32 + i], Aat[v * 32 + j], acc);
            gt[j * 32 + i] = acc;
        }
    }
    __syncthreads();
    // out[c,i] = elu( sum_j gt[j,i] * wht[c,j] )
    {
        int i = tid & 31, cg = tid >> 5;
        float greg[32];
#pragma unroll
        for (int j = 0; j < 32; ++j) greg[j] = gt[j * 32 + i];
        for (int k = 0; k < 32; ++k) {
            int c = cg * 32 + k;
            float acc = 0.f;
#pragma unroll
            for (int j8 = 0; j8 < 8; ++j8) {
                float4 w4 = ((float4*)wht)[c * 8 + j8];
                acc = fmaf(greg[4 * j8 + 0], w4.x, acc);
                acc = fmaf(greg[4 * j8 + 1], w4.y, acc);
                acc = fmaf(greg[4 * j8 + 2], w4.z, acc);
                acc = fmaf(greg[4 * j8 + 3], w4.w, acc);
            }
            float o = acc > 0.f ? acc : expm1f(acc);
            out[(((size_t)(n * 256 + c)) * 32 + tp) * 32 + i] = o;
        }
    }
}

extern "C" void kernel_launch(void* const* d_in, const int* in_sizes, int n_in,
                              void* d_out, int out_size, void* d_ws, size_t ws_size,
                              hipStream_t stream) {
    const float* h  = (const float*)d_in[0];
    const float* Wm = (const float*)d_in[1];
    const float* a  = (const float*)d_in[2];
    const float* B  = (const float*)d_in[3];
    float* out = (float*)d_out;
    float* ws  = (float*)d_ws;

    float* WhT = ws;
    float* s_g = ws + 1048576;

    hipMemsetAsync(s_g, 0, 2048 * sizeof(float), stream);
    k_whs<<<1024, 256, 0, stream>>>(h, Wm, a, WhT, s_g);
    k_outf<<<128, 256, 0, stream>>>(WhT, s_g, B, out);
}

// Round 3
// 84.668 us; speedup vs baseline: 1.0430x; 1.0430x over previous
//
#include <hip/hip_runtime.h>
#include <math.h>

// GATLayerTemporal: N=4, H=16, W=16, T=32, V=32, HW=256
// e[n,i,j,2m] = s[n,i,m]; e[n,i,j,2m+1] = s[n,j,m]
// s[n,v,m] = sum_{w<16,t<32} Wh[n,v,m*16+w,t] * a[w*32+t]
// out[n,c,t',i] = elu( sum_j G_t'[i,j] * Wh[n,j,c,t'] ),
//   G_t'[i,j] = sum_v adjn[v,i] * att_t'[v,j]
//
// ws: WhT [N][T][HW][V] (1048576 f32) | s [N][V][16] (2048 f32, atomicAdd, memset 0)

#define ALPHA 0.2f

// ---- Kernel A: per (n,c) 32x32 GEMM tile; fused s-logit atomics; coalesced WhT ----
__global__ __launch_bounds__(256) void k_whs(const float* __restrict__ h,
                                             const float* __restrict__ Wm,
                                             const float* __restrict__ a,
                                             float* __restrict__ WhT,
                                             float* __restrict__ s_g) {
    __shared__ float ht[1024];   // [t][v]
    __shared__ float Wl[1024];   // [t][tp]
    __shared__ float S[32 * 33]; // [tp][v], padded
    int tid = threadIdx.x, bid = blockIdx.x;
    int n = bid >> 8, c = bid & 255;
    int w = c & 15, m = c >> 4;
    ((float4*)ht)[tid] = ((const float4*)(h + ((size_t)(n * 256 + c)) * 1024))[tid];
    ((float4*)Wl)[tid] = ((const float4*)Wm)[tid];
    __syncthreads();
    int tp = tid & 31, v0 = tid >> 5;
    float acc[4] = {0.f, 0.f, 0.f, 0.f};
#pragma unroll
    for (int t = 0; t < 32; ++t) {
        float wl = Wl[t * 32 + tp];
#pragma unroll
        for (int p = 0; p < 4; ++p)
            acc[p] = fmaf(ht[t * 32 + v0 + 8 * p], wl, acc[p]);
    }
    float av = a[w * 32 + tp];
#pragma unroll
    for (int p = 0; p < 4; ++p) {
        S[tp * 33 + v0 + 8 * p] = acc[p];
        float contrib = acc[p] * av;
        // reduce over tp within the 32-lane half-wave
#pragma unroll
        for (int msk = 1; msk <= 16; msk <<= 1) contrib += __shfl_xor(contrib, msk);
        if (tp == 0) atomicAdd(&s_g[(n * 32 + v0 + 8 * p) * 16 + m], contrib);
    }
    __syncthreads();
#pragma unroll
    for (int p = 0; p < 4; ++p) {
        int r = (tid >> 5) + 8 * p, vc = tid & 31;
        WhT[(((size_t)(n * 32 + r)) * 256 + c) * 32 + vc] = S[r * 33 + vc];
    }
}

// ---- Kernel B: per (n,t',chunk) block: adjnorm + softmax stats + attention + G + output ----
// 512 blocks (2/CU); each handles 64 of the 256 c-rows.
__global__ __launch_bounds__(256) void k_outf(const float* __restrict__ WhT,
                                              const float* __restrict__ s_g,
                                              const float* __restrict__ B,
                                              float* __restrict__ out) {
    __shared__ float wht[2048];  // [c_local][j], 64 rows
    __shared__ float adjn[1024]; // raw then normalized [v][i]
    __shared__ float Aat[1024];  // attention [v][j]
    __shared__ float gt[1024];   // [j][i]
    __shared__ float u[512];     // lrelu'd s for this n: [v][16]
    __shared__ float mxs[32], Es[32], dis[32];
    __shared__ float red[8];
    __shared__ float mnmx[2];
    int tid = threadIdx.x, bid = blockIdx.x;
    int n = bid >> 7, r = bid & 127, tp = r >> 2, chunk = r & 3;
    int m = tp >> 1, odd = tp & 1;
    const float4* src = (const float4*)(WhT + (((size_t)(n * 32 + tp)) * 256 + chunk * 64) * 32);
    ((float4*)wht)[tid] = src[tid];
    ((float4*)wht)[tid + 256] = src[tid + 256];

    // stage B_adj (+eps +eye), local min/max
    float4 b4 = ((const float4*)B)[tid];
    float lmn = 1e30f, lmx = -1e30f;
    const float* b4f = (const float*)&b4;
#pragma unroll
    for (int k = 0; k < 4; ++k) {
        int e = tid * 4 + k;
        float x = b4f[k] + 1e-6f + (((e >> 5) == (e & 31)) ? 1.0f : 0.0f);
        lmn = fminf(lmn, x); lmx = fmaxf(lmx, x);
        adjn[e] = x;
    }
    for (int msk = 1; msk < 64; msk <<= 1) {
        lmn = fminf(lmn, __shfl_xor(lmn, msk));
        lmx = fmaxf(lmx, __shfl_xor(lmx, msk));
    }
    if ((tid & 63) == 0) { red[tid >> 6] = lmn; red[4 + (tid >> 6)] = lmx; }

    // u = leaky_relu(s[n])
    {
        float s0 = s_g[n * 512 + tid];
        float s1 = s_g[n * 512 + 256 + tid];
        u[tid] = s0 > 0.f ? s0 : ALPHA * s0;
        u[tid + 256] = s1 > 0.f ? s1 : ALPHA * s1;
    }
    __syncthreads();
    if (tid == 0) {
        float mn = fminf(fminf(red[0], red[1]), fminf(red[2], red[3]));
        float mx = fmaxf(fmaxf(red[4], red[5]), fmaxf(red[6], red[7]));
        mnmx[0] = mn; mnmx[1] = 1.0f / (mx - mn);
    }
    __syncthreads();
    float mn = mnmx[0], inv = mnmx[1];
    if (tid < 32) {
        float rs = 0.f;
#pragma unroll
        for (int k = 0; k < 32; ++k) {
            int i = (k + tid) & 31; // staggered: conflict-free
            rs += (adjn[tid * 32 + i] - mn) * inv;
        }
        dis[tid] = rsqrtf(rs);
    } else if (tid >= 64 && tid < 96) {
        int v = tid - 64;
        float mxv = -1e30f;
#pragma unroll
        for (int k = 0; k < 16; ++k) mxv = fmaxf(mxv, u[v * 16 + k]);
        float es = 0.f;
#pragma unroll
        for (int k = 0; k < 16; ++k) es += expf(u[v * 16 + k] - mxv);
        mxs[v] = mxv; Es[v] = es;
    }
    __syncthreads();
    // normalize adjn in place; compute attention
    {
        int j = tid & 31, v0g = tid >> 5;
#pragma unroll
        for (int k = 0; k < 4; ++k) {
            int e = tid * 4 + k;
            adjn[e] = (adjn[e] - mn) * inv * dis[e >> 5] * dis[e & 31];
        }
#pragma unroll
        for (int p = 0; p < 4; ++p) {
            int v = v0g + 8 * p;
            float mv = mxs[v], mj = mxs[j];
            float M = fmaxf(mv, mj);
            float Z = Es[v] * expf(mv - M) + Es[j] * expf(mj - M);
            float num = expf((odd ? u[j * 16 + m] : u[v * 16 + m]) - M);
            Aat[v * 32 + j] = num / Z;
        }
    }
    __syncthreads();
    // gt[j][i] = sum_v adjn[v,i] * Aat[v,j]
    {
        int i = tid & 31, j0 = tid >> 5;
#pragma unroll
        for (int p = 0; p < 4; ++p) {
            int j = j0 + 8 * p;
            float acc = 0.f;
#pragma unroll
            for (int v = 0; v < 32; ++v)
                acc = fmaf(adjn[v * 32 + i], Aat[v * 32 + j], acc);
            gt[j * 32 + i] = acc;
        }
    }
    __syncthreads();
    // out[c,i] = elu( sum_j gt[j,i] * wht[c_local,j] )
    {
        int i = tid & 31, cg = tid >> 5;
        float greg[32];
#pragma unroll
        for (int j = 0; j < 32; ++j) greg[j] = gt[j * 32 + i];
#pragma unroll
        for (int k = 0; k < 8; ++k) {
            int cl = cg * 8 + k;
            int c = chunk * 64 + cl;
            float acc = 0.f;
#pragma unroll
            for (int j8 = 0; j8 < 8; ++j8) {
                float4 w4 = ((float4*)wht)[cl * 8 + j8];
                acc = fmaf(greg[4 * j8 + 0], w4.x, acc);
                acc = fmaf(greg[4 * j8 + 1], w4.y, acc);
                acc = fmaf(greg[4 * j8 + 2], w4.z, acc);
                acc = fmaf(greg[4 * j8 + 3], w4.w, acc);
            }
            float o = acc > 0.f ? acc : expm1f(acc);
            out[(((size_t)(n * 256 + c)) * 32 + tp) * 32 + i] = o;
        }
    }
}

extern "C" void kernel_launch(void* const* d_in, const int* in_sizes, int n_in,
                              void* d_out, int out_size, void* d_ws, size_t ws_size,
                              hipStream_t stream) {
    const float* h  = (const float*)d_in[0];
    const float* Wm = (const float*)d_in[1];
    const float* a  = (const float*)d_in[2];
    const float* B  = (const float*)d_in[3];
    float* out = (float*)d_out;
    float* ws  = (float*)d_ws;

    float* WhT = ws;
    float* s_g = ws + 1048576;

    hipMemsetAsync(s_g, 0, 2048 * sizeof(float), stream);
    k_whs<<<1024, 256, 0, stream>>>(h, Wm, a, WhT, s_g);
    k_outf<<<512, 256, 0, stream>>>(WhT, s_g, B, out);
}